// Round 7
// baseline (356.240 us; speedup 1.0000x reference)
//
#include <hip/hip_runtime.h>

#define N_NODES 100000
#define N_EDGES 1600000
#define IN_DIM 256
#define HIDDEN 128
#define OUT_DIM 64

#define NBIN 391       // coarse bins of 256 nodes: ceil(100000/256)
#define NBLK3 256      // histogram/scatter blocks
#define CHUNK 6250     // edges per block: N_EDGES / NBLK3 exactly
#define NMAT (NBIN * NBLK3)      // 100096 = scan length
#define NBLK_SCAN (NMAT / 256)   // 391 exactly
#define CAP 6144       // max edges per bin (mean 4096, sigma 64 -> 32 sigma margin)

#define LDK1 264       // LDS leading dim (256 k + 8 pad) for W1 tile, bf16
#define LDK2 136       // LDS leading dim (128 k + 8 pad) for W2 tile, bf16

typedef __bf16 bf16x8 __attribute__((ext_vector_type(8)));
typedef __bf16 bf16x4 __attribute__((ext_vector_type(4)));
typedef float f32x4 __attribute__((ext_vector_type(4)));

// ---------------------------------------------------------------------------
// P1: per-(bin,block) histogram. cnt2[k*NBLK3 + b] = #edges of block b in bin k
// ---------------------------------------------------------------------------
__launch_bounds__(256)
__global__ void k_hist(const int* __restrict__ dst, int* __restrict__ cnt2) {
    __shared__ int hist[NBIN];
    for (int i = threadIdx.x; i < NBIN; i += 256) hist[i] = 0;
    __syncthreads();
    int base = blockIdx.x * CHUNK;
    for (int i = threadIdx.x; i < CHUNK; i += 256)
        atomicAdd(&hist[dst[base + i] >> 8], 1);
    __syncthreads();
    for (int k = threadIdx.x; k < NBIN; k += 256)
        cnt2[k * NBLK3 + blockIdx.x] = hist[k];
}

// ---------------------------------------------------------------------------
// P2: 3-kernel exclusive scan over cnt2 (in place), length NMAT
// ---------------------------------------------------------------------------
__global__ void k_scan1(int* __restrict__ a, int* __restrict__ bsum) {
    __shared__ int tmp[256];
    int t = threadIdx.x;
    int i = blockIdx.x * 256 + t;
    int v = a[i];
    tmp[t] = v;
    __syncthreads();
    #pragma unroll
    for (int off = 1; off < 256; off <<= 1) {
        int p = (t >= off) ? tmp[t - off] : 0;
        __syncthreads();
        tmp[t] += p;
        __syncthreads();
    }
    a[i] = tmp[t] - v;  // exclusive
    if (t == 255) bsum[blockIdx.x] = tmp[255];
}

__global__ void k_scan2(int* __restrict__ bsum) {
    __shared__ int tmp[512];
    int t = threadIdx.x;
    int v = (t < NBLK_SCAN) ? bsum[t] : 0;
    tmp[t] = v;
    __syncthreads();
    #pragma unroll
    for (int off = 1; off < 512; off <<= 1) {
        int p = (t >= off) ? tmp[t - off] : 0;
        __syncthreads();
        tmp[t] += p;
        __syncthreads();
    }
    if (t < NBLK_SCAN) bsum[t] = tmp[t] - v;
}

__global__ void k_scan3(int* __restrict__ a, const int* __restrict__ bsum) {
    int i = blockIdx.x * 256 + threadIdx.x;
    a[i] += bsum[blockIdx.x];
}

// ---------------------------------------------------------------------------
// P3: scatter edges into bin-grouped ebuf; each (block,bin) range is exclusive
// packed entry: src*256 | (dst & 255)
// ---------------------------------------------------------------------------
__launch_bounds__(256)
__global__ void k_scatter_bins(const int* __restrict__ src, const int* __restrict__ dst,
                               const int* __restrict__ off2,
                               unsigned int* __restrict__ ebuf) {
    __shared__ int cursor[NBIN];
    for (int k = threadIdx.x; k < NBIN; k += 256)
        cursor[k] = off2[k * NBLK3 + blockIdx.x];
    __syncthreads();
    int base = blockIdx.x * CHUNK;
    for (int i = threadIdx.x; i < CHUNK; i += 256) {
        int s = src[base + i], d = dst[base + i];
        int pos = atomicAdd(&cursor[d >> 8], 1);
        ebuf[pos] = ((unsigned)s << 8) | (unsigned)(d & 255);
    }
}

// ---------------------------------------------------------------------------
// P4: fine counting-sort within each bin (all in LDS), coalesced esrc output;
// fuses deg -> dinv and rowstart production.
// ---------------------------------------------------------------------------
__launch_bounds__(256)
__global__ void k_fine(const unsigned int* __restrict__ ebuf, const int* __restrict__ off2,
                       int* __restrict__ esrc, int* __restrict__ rowstart,
                       float* __restrict__ dinv) {
    __shared__ int hist[256];
    __shared__ int tmp[256];
    __shared__ int nodeoff[256];
    __shared__ int cursor[256];
    __shared__ unsigned int ed[CAP];
    __shared__ int sOut[CAP];

    const int k = blockIdx.x;
    const int t = threadIdx.x;
    const int e0 = off2[k * NBLK3];
    const int e1 = (k + 1 < NBIN) ? off2[(k + 1) * NBLK3] : N_EDGES;
    int m = e1 - e0;
    if (m > CAP) m = CAP;  // safety clamp (statistically unreachable)

    hist[t] = 0;
    __syncthreads();
    for (int i = t; i < m; i += 256) {
        unsigned v = ebuf[e0 + i];
        ed[i] = v;
        atomicAdd(&hist[v & 255], 1);
    }
    __syncthreads();

    // exclusive scan of hist -> nodeoff
    int v = hist[t];
    tmp[t] = v;
    __syncthreads();
    #pragma unroll
    for (int off = 1; off < 256; off <<= 1) {
        int p = (t >= off) ? tmp[t - off] : 0;
        __syncthreads();
        tmp[t] += p;
        __syncthreads();
    }
    nodeoff[t] = tmp[t] - v;
    cursor[t] = tmp[t] - v;
    __syncthreads();

    // place src values by node
    for (int i = t; i < m; i += 256) {
        unsigned e = ed[i];
        int pos = atomicAdd(&cursor[e & 255], 1);
        sOut[pos] = (int)(e >> 8);
    }
    __syncthreads();

    // stream out coalesced
    for (int i = t; i < m; i += 256) esrc[e0 + i] = sOut[i];

    int n = k * 256 + t;
    if (n < N_NODES) {
        rowstart[n] = e0 + nodeoff[t];
        dinv[n] = rsqrtf((float)hist[t] + 1.0f);
    }
    if (k == 0 && t == 0) rowstart[N_NODES] = N_EDGES;
}

// ---------------------------------------------------------------------------
// GEMM1 (bf16 MFMA): H[M][128] = bf16(X[M][256]) @ bf16(W1[256][128])
// W1 staged ONCE into LDS (bf16, [col][k], LDK1=264) -> barrier-free K-loop.
// A-fragments stream straight from global X (f32->bf16 in regs, no LDS).
// Block 128x128, 4 waves 2x2, wave tile 64x64 (4x4 16x16x32 MFMAs x 8 ksteps).
// ---------------------------------------------------------------------------
__launch_bounds__(256, 2)
__global__ void k_gemm1(const float* __restrict__ X, const float* __restrict__ W1,
                        __bf16* __restrict__ H) {
    __shared__ __attribute__((aligned(16))) __bf16 Bs[HIDDEN * LDK1];  // 67.6 KB

    const int t = threadIdx.x;
    const int wave = t >> 6;
    const int lane = t & 63;
    const int wr = wave >> 1, wc = wave & 1;
    const int lm = lane & 15;
    const int q = lane >> 4;
    const int row0 = blockIdx.x * 128 + wr * 64;
    const int colbase = wc * 64;

    // stage W1 -> Bs[col][k] (transposed, bf16). 4096 k-pair items, 16/thread.
    // item: k2 in [0,128), cg in [0,32): read f32x4 at rows 2k2,2k2+1 col 4cg,
    // write 4 bf16x2 pairs (4 B each).
    #pragma unroll
    for (int it = 0; it < 16; ++it) {
        int idx = it * 256 + t;
        int k2 = idx >> 5;
        int c = (idx & 31) * 4;
        float4 v0 = *(const float4*)&W1[(2 * k2) * HIDDEN + c];
        float4 v1 = *(const float4*)&W1[(2 * k2 + 1) * HIDDEN + c];
        const float lo[4] = {v0.x, v0.y, v0.z, v0.w};
        const float hi[4] = {v1.x, v1.y, v1.z, v1.w};
        #pragma unroll
        for (int i = 0; i < 4; ++i) {
            __bf16 pair[2] = {(__bf16)lo[i], (__bf16)hi[i]};
            *(unsigned int*)&Bs[(c + i) * LDK1 + 2 * k2] = *(unsigned int*)pair;
        }
    }
    __syncthreads();

    // clamped A row pointers
    const float* xp[4];
    #pragma unroll
    for (int mi = 0; mi < 4; ++mi) {
        int r = row0 + mi * 16 + lm;
        if (r > N_NODES - 1) r = N_NODES - 1;
        xp[mi] = &X[r * IN_DIM];
    }

    f32x4 acc[4][4] = {};

    #pragma unroll
    for (int ks = 0; ks < 8; ++ks) {
        bf16x8 af[4];
        #pragma unroll
        for (int mi = 0; mi < 4; ++mi) {
            float4 a0 = *(const float4*)&xp[mi][ks * 32 + q * 8];
            float4 a1 = *(const float4*)&xp[mi][ks * 32 + q * 8 + 4];
            bf16x8 f;
            f[0] = (__bf16)a0.x; f[1] = (__bf16)a0.y;
            f[2] = (__bf16)a0.z; f[3] = (__bf16)a0.w;
            f[4] = (__bf16)a1.x; f[5] = (__bf16)a1.y;
            f[6] = (__bf16)a1.z; f[7] = (__bf16)a1.w;
            af[mi] = f;
        }
        bf16x8 bfr[4];
        #pragma unroll
        for (int ni = 0; ni < 4; ++ni)
            bfr[ni] = *(const bf16x8*)&Bs[(colbase + ni * 16 + lm) * LDK1 + ks * 32 + q * 8];
        #pragma unroll
        for (int mi = 0; mi < 4; ++mi)
            #pragma unroll
            for (int ni = 0; ni < 4; ++ni)
                acc[mi][ni] = __builtin_amdgcn_mfma_f32_16x16x32_bf16(
                    af[mi], bfr[ni], acc[mi][ni], 0, 0, 0);
    }

    // epilogue: C/D layout col=lm, row=q*4+r
    #pragma unroll
    for (int mi = 0; mi < 4; ++mi) {
        #pragma unroll
        for (int r = 0; r < 4; ++r) {
            int grow = row0 + mi * 16 + q * 4 + r;
            if (grow < N_NODES) {
                #pragma unroll
                for (int ni = 0; ni < 4; ++ni)
                    H[grow * HIDDEN + colbase + ni * 16 + lm] = (__bf16)acc[mi][ni][r];
            }
        }
    }
}

// ---------------------------------------------------------------------------
// gather layer1: AGG[n] = bf16(relu( sum coef*H[src] + dinv^2*H[n] + b1 ))
// 16 lanes x bf16x8 per node, 16 nodes/block, edge loop unrolled x4 for MLP
// ---------------------------------------------------------------------------
__launch_bounds__(256)
__global__ void k_gather1(const int* __restrict__ rowstart, const int* __restrict__ esrc,
                          const float* __restrict__ dinv,
                          const __bf16* __restrict__ H, const float* __restrict__ b1,
                          __bf16* __restrict__ AGG) {
    int n = blockIdx.x * 16 + (threadIdx.x >> 4);
    if (n >= N_NODES) return;
    int j = (threadIdx.x & 15) * 8;

    float dn = dinv[n];
    float s = dn * dn;
    bf16x8 h = *(const bf16x8*)&H[n * HIDDEN + j];
    float acc[8];
    #pragma unroll
    for (int i = 0; i < 8; ++i) acc[i] = (float)h[i] * s;

    int p0 = rowstart[n], p1 = rowstart[n + 1];
    int p = p0;
    for (; p + 3 < p1; p += 4) {
        int s0 = esrc[p + 0], s1 = esrc[p + 1], s2 = esrc[p + 2], s3 = esrc[p + 3];
        float c0 = dinv[s0] * dn, c1 = dinv[s1] * dn;
        float c2 = dinv[s2] * dn, c3 = dinv[s3] * dn;
        bf16x8 v0 = *(const bf16x8*)&H[s0 * HIDDEN + j];
        bf16x8 v1 = *(const bf16x8*)&H[s1 * HIDDEN + j];
        bf16x8 v2 = *(const bf16x8*)&H[s2 * HIDDEN + j];
        bf16x8 v3 = *(const bf16x8*)&H[s3 * HIDDEN + j];
        #pragma unroll
        for (int i = 0; i < 8; ++i) acc[i] = fmaf((float)v0[i], c0, acc[i]);
        #pragma unroll
        for (int i = 0; i < 8; ++i) acc[i] = fmaf((float)v1[i], c1, acc[i]);
        #pragma unroll
        for (int i = 0; i < 8; ++i) acc[i] = fmaf((float)v2[i], c2, acc[i]);
        #pragma unroll
        for (int i = 0; i < 8; ++i) acc[i] = fmaf((float)v3[i], c3, acc[i]);
    }
    for (; p < p1; ++p) {
        int sidx = esrc[p];
        float c = dinv[sidx] * dn;
        bf16x8 v = *(const bf16x8*)&H[sidx * HIDDEN + j];
        #pragma unroll
        for (int i = 0; i < 8; ++i) acc[i] = fmaf((float)v[i], c, acc[i]);
    }

    float4 bb0 = *(const float4*)&b1[j];
    float4 bb1 = *(const float4*)&b1[j + 4];
    bf16x8 o;
    o[0] = (__bf16)fmaxf(acc[0] + bb0.x, 0.f);
    o[1] = (__bf16)fmaxf(acc[1] + bb0.y, 0.f);
    o[2] = (__bf16)fmaxf(acc[2] + bb0.z, 0.f);
    o[3] = (__bf16)fmaxf(acc[3] + bb0.w, 0.f);
    o[4] = (__bf16)fmaxf(acc[4] + bb1.x, 0.f);
    o[5] = (__bf16)fmaxf(acc[5] + bb1.y, 0.f);
    o[6] = (__bf16)fmaxf(acc[6] + bb1.z, 0.f);
    o[7] = (__bf16)fmaxf(acc[7] + bb1.w, 0.f);
    *(bf16x8*)&AGG[n * HIDDEN + j] = o;
}

// ---------------------------------------------------------------------------
// GEMM2 (bf16 MFMA): H2[M][64] = AGG[M][128] @ bf16(W2[128][64])
// W2 staged once into LDS; barrier-free K-loop; A = bf16 direct global loads.
// Block 256 rows x 64 cols, 4 waves stacked in m, wave tile 64x64, 4 ksteps.
// ---------------------------------------------------------------------------
__launch_bounds__(256, 2)
__global__ void k_gemm2(const __bf16* __restrict__ AGG, const float* __restrict__ W2,
                        __bf16* __restrict__ H2) {
    __shared__ __attribute__((aligned(16))) __bf16 Bs[OUT_DIM * LDK2];  // 17.4 KB

    const int t = threadIdx.x;
    const int wave = t >> 6;
    const int lane = t & 63;
    const int lm = lane & 15;
    const int q = lane >> 4;
    const int row0 = blockIdx.x * 256 + wave * 64;

    // stage W2 -> Bs[col][k]: 1024 k-pair items (k2 in [0,64), cg in [0,16)),
    // 4 per thread.
    #pragma unroll
    for (int it = 0; it < 4; ++it) {
        int idx = it * 256 + t;
        int k2 = idx >> 4;
        int c = (idx & 15) * 4;
        float4 v0 = *(const float4*)&W2[(2 * k2) * OUT_DIM + c];
        float4 v1 = *(const float4*)&W2[(2 * k2 + 1) * OUT_DIM + c];
        const float lo[4] = {v0.x, v0.y, v0.z, v0.w};
        const float hi[4] = {v1.x, v1.y, v1.z, v1.w};
        #pragma unroll
        for (int i = 0; i < 4; ++i) {
            __bf16 pair[2] = {(__bf16)lo[i], (__bf16)hi[i]};
            *(unsigned int*)&Bs[(c + i) * LDK2 + 2 * k2] = *(unsigned int*)pair;
        }
    }
    __syncthreads();

    const __bf16* ap[4];
    #pragma unroll
    for (int mi = 0; mi < 4; ++mi) {
        int r = row0 + mi * 16 + lm;
        if (r > N_NODES - 1) r = N_NODES - 1;
        ap[mi] = &AGG[r * HIDDEN];
    }

    f32x4 acc[4][4] = {};

    #pragma unroll
    for (int ks = 0; ks < 4; ++ks) {
        bf16x8 af[4];
        #pragma unroll
        for (int mi = 0; mi < 4; ++mi)
            af[mi] = *(const bf16x8*)&ap[mi][ks * 32 + q * 8];
        bf16x8 bfr[4];
        #pragma unroll
        for (int ni = 0; ni < 4; ++ni)
            bfr[ni] = *(const bf16x8*)&Bs[(ni * 16 + lm) * LDK2 + ks * 32 + q * 8];
        #pragma unroll
        for (int mi = 0; mi < 4; ++mi)
            #pragma unroll
            for (int ni = 0; ni < 4; ++ni)
                acc[mi][ni] = __builtin_amdgcn_mfma_f32_16x16x32_bf16(
                    af[mi], bfr[ni], acc[mi][ni], 0, 0, 0);
    }

    #pragma unroll
    for (int mi = 0; mi < 4; ++mi) {
        #pragma unroll
        for (int r = 0; r < 4; ++r) {
            int grow = row0 + mi * 16 + q * 4 + r;
            if (grow < N_NODES) {
                #pragma unroll
                for (int ni = 0; ni < 4; ++ni)
                    H2[grow * OUT_DIM + ni * 16 + lm] = (__bf16)acc[mi][ni][r];
            }
        }
    }
}

// ---------------------------------------------------------------------------
// gather layer2: OUT[n] = relu( sum coef*H2[src] + dinv^2*H2[n] + b2 )  (f32 out)
// 8 lanes x bf16x8 per node, 32 nodes/block, edge loop unrolled x4
// ---------------------------------------------------------------------------
__launch_bounds__(256)
__global__ void k_gather2(const int* __restrict__ rowstart, const int* __restrict__ esrc,
                          const float* __restrict__ dinv,
                          const __bf16* __restrict__ H2, const float* __restrict__ b2,
                          float* __restrict__ OUT) {
    int n = blockIdx.x * 32 + (threadIdx.x >> 3);
    if (n >= N_NODES) return;
    int j = (threadIdx.x & 7) * 8;

    float dn = dinv[n];
    float s = dn * dn;
    bf16x8 h = *(const bf16x8*)&H2[n * OUT_DIM + j];
    float acc[8];
    #pragma unroll
    for (int i = 0; i < 8; ++i) acc[i] = (float)h[i] * s;

    int p0 = rowstart[n], p1 = rowstart[n + 1];
    int p = p0;
    for (; p + 3 < p1; p += 4) {
        int s0 = esrc[p + 0], s1 = esrc[p + 1], s2 = esrc[p + 2], s3 = esrc[p + 3];
        float c0 = dinv[s0] * dn, c1 = dinv[s1] * dn;
        float c2 = dinv[s2] * dn, c3 = dinv[s3] * dn;
        bf16x8 v0 = *(const bf16x8*)&H2[s0 * OUT_DIM + j];
        bf16x8 v1 = *(const bf16x8*)&H2[s1 * OUT_DIM + j];
        bf16x8 v2 = *(const bf16x8*)&H2[s2 * OUT_DIM + j];
        bf16x8 v3 = *(const bf16x8*)&H2[s3 * OUT_DIM + j];
        #pragma unroll
        for (int i = 0; i < 8; ++i) acc[i] = fmaf((float)v0[i], c0, acc[i]);
        #pragma unroll
        for (int i = 0; i < 8; ++i) acc[i] = fmaf((float)v1[i], c1, acc[i]);
        #pragma unroll
        for (int i = 0; i < 8; ++i) acc[i] = fmaf((float)v2[i], c2, acc[i]);
        #pragma unroll
        for (int i = 0; i < 8; ++i) acc[i] = fmaf((float)v3[i], c3, acc[i]);
    }
    for (; p < p1; ++p) {
        int sidx = esrc[p];
        float c = dinv[sidx] * dn;
        bf16x8 v = *(const bf16x8*)&H2[sidx * OUT_DIM + j];
        #pragma unroll
        for (int i = 0; i < 8; ++i) acc[i] = fmaf((float)v[i], c, acc[i]);
    }

    float4 bb0 = *(const float4*)&b2[j];
    float4 bb1 = *(const float4*)&b2[j + 4];
    float4 o0, o1;
    o0.x = fmaxf(acc[0] + bb0.x, 0.f);
    o0.y = fmaxf(acc[1] + bb0.y, 0.f);
    o0.z = fmaxf(acc[2] + bb0.z, 0.f);
    o0.w = fmaxf(acc[3] + bb0.w, 0.f);
    o1.x = fmaxf(acc[4] + bb1.x, 0.f);
    o1.y = fmaxf(acc[5] + bb1.y, 0.f);
    o1.z = fmaxf(acc[6] + bb1.z, 0.f);
    o1.w = fmaxf(acc[7] + bb1.w, 0.f);
    *(float4*)&OUT[n * OUT_DIM + j] = o0;
    *(float4*)&OUT[n * OUT_DIM + j + 4] = o1;
}

extern "C" void kernel_launch(void* const* d_in, const int* in_sizes, int n_in,
                              void* d_out, int out_size, void* d_ws, size_t ws_size,
                              hipStream_t stream) {
    const float* x  = (const float*)d_in[0];
    const int* ei   = (const int*)d_in[1];
    const float* W1 = (const float*)d_in[2];
    const float* b1 = (const float*)d_in[3];
    const float* W2 = (const float*)d_in[4];
    const float* b2 = (const float*)d_in[5];
    float* out = (float*)d_out;

    const int* src = ei;
    const int* dst = ei + N_EDGES;

    char* ws = (char*)d_ws;
    int*          cnt2     = (int*)         (ws + 0x000000);   // 400,384 B (becomes off2)
    int*          bsum     = (int*)         (ws + 0x080000);   // 1,564 B
    int*          rowstart = (int*)         (ws + 0x090000);   // 400,004 B
    float*        dinv     = (float*)       (ws + 0x100000);   // 400,000 B
    unsigned int* ebuf     = (unsigned int*)(ws + 0x180000);   // 6.4 MB
    int*          esrc     = (int*)         (ws + 0x800000);   // 6.4 MB
    __bf16*       h1       = (__bf16*)      (ws + 0xE80000);   // 25.6 MB
    __bf16*       agg1     = (__bf16*)      (ws + 0x2880000);  // 25.6 MB
    __bf16*       h2       = (__bf16*)      (ws + 0x4280000);  // 12.8 MB

    // CSR build (two-level counting sort; no random global scatters)
    k_hist<<<NBLK3, 256, 0, stream>>>(dst, cnt2);
    k_scan1<<<NBLK_SCAN, 256, 0, stream>>>(cnt2, bsum);
    k_scan2<<<1, 512, 0, stream>>>(bsum);
    k_scan3<<<NBLK_SCAN, 256, 0, stream>>>(cnt2, bsum);
    k_scatter_bins<<<NBLK3, 256, 0, stream>>>(src, dst, cnt2, ebuf);
    k_fine<<<NBIN, 256, 0, stream>>>(ebuf, cnt2, esrc, rowstart, dinv);

    // layer 1
    k_gemm1<<<(N_NODES + 127) / 128, 256, 0, stream>>>(x, W1, h1);
    k_gather1<<<(N_NODES + 15) / 16, 256, 0, stream>>>(rowstart, esrc, dinv, h1, b1, agg1);
    // layer 2
    k_gemm2<<<(N_NODES + 255) / 256, 256, 0, stream>>>(agg1, W2, h2);
    k_gather2<<<(N_NODES + 31) / 32, 256, 0, stream>>>(rowstart, esrc, dinv, h2, b2, out);
}

// Round 8
// 353.328 us; speedup vs baseline: 1.0082x; 1.0082x over previous
//
#include <hip/hip_runtime.h>

#define N_NODES 100000
#define N_EDGES 1600000
#define IN_DIM 256
#define HIDDEN 128
#define OUT_DIM 64

#define NBIN 391       // coarse bins of 256 nodes: ceil(100000/256)
#define NBLK3 256      // histogram/scatter blocks
#define CHUNK 6250     // edges per block: N_EDGES / NBLK3 exactly
#define NMAT (NBIN * NBLK3)      // 100096 = scan length
#define NBLK_SCAN (NMAT / 256)   // 391 exactly
#define CAP 6144       // max edges per bin (mean 4096, sigma 64 -> 32 sigma margin)

typedef __bf16 bf16x8 __attribute__((ext_vector_type(8)));
typedef __bf16 bf16x4 __attribute__((ext_vector_type(4)));
typedef float f32x4 __attribute__((ext_vector_type(4)));

// ---------------------------------------------------------------------------
// P1: per-(bin,block) histogram
// ---------------------------------------------------------------------------
__launch_bounds__(256)
__global__ void k_hist(const int* __restrict__ dst, int* __restrict__ cnt2) {
    __shared__ int hist[NBIN];
    for (int i = threadIdx.x; i < NBIN; i += 256) hist[i] = 0;
    __syncthreads();
    int base = blockIdx.x * CHUNK;
    for (int i = threadIdx.x; i < CHUNK; i += 256)
        atomicAdd(&hist[dst[base + i] >> 8], 1);
    __syncthreads();
    for (int k = threadIdx.x; k < NBIN; k += 256)
        cnt2[k * NBLK3 + blockIdx.x] = hist[k];
}

// ---------------------------------------------------------------------------
// P2: 3-kernel exclusive scan over cnt2 (in place), length NMAT
// ---------------------------------------------------------------------------
__global__ void k_scan1(int* __restrict__ a, int* __restrict__ bsum) {
    __shared__ int tmp[256];
    int t = threadIdx.x;
    int i = blockIdx.x * 256 + t;
    int v = a[i];
    tmp[t] = v;
    __syncthreads();
    #pragma unroll
    for (int off = 1; off < 256; off <<= 1) {
        int p = (t >= off) ? tmp[t - off] : 0;
        __syncthreads();
        tmp[t] += p;
        __syncthreads();
    }
    a[i] = tmp[t] - v;  // exclusive
    if (t == 255) bsum[blockIdx.x] = tmp[255];
}

__global__ void k_scan2(int* __restrict__ bsum) {
    __shared__ int tmp[512];
    int t = threadIdx.x;
    int v = (t < NBLK_SCAN) ? bsum[t] : 0;
    tmp[t] = v;
    __syncthreads();
    #pragma unroll
    for (int off = 1; off < 512; off <<= 1) {
        int p = (t >= off) ? tmp[t - off] : 0;
        __syncthreads();
        tmp[t] += p;
        __syncthreads();
    }
    if (t < NBLK_SCAN) bsum[t] = tmp[t] - v;
}

__global__ void k_scan3(int* __restrict__ a, const int* __restrict__ bsum) {
    int i = blockIdx.x * 256 + threadIdx.x;
    a[i] += bsum[blockIdx.x];
}

// ---------------------------------------------------------------------------
// P3: scatter edges into bin-grouped ebuf (packed src*256 | dst&255)
// ---------------------------------------------------------------------------
__launch_bounds__(256)
__global__ void k_scatter_bins(const int* __restrict__ src, const int* __restrict__ dst,
                               const int* __restrict__ off2,
                               unsigned int* __restrict__ ebuf) {
    __shared__ int cursor[NBIN];
    for (int k = threadIdx.x; k < NBIN; k += 256)
        cursor[k] = off2[k * NBLK3 + blockIdx.x];
    __syncthreads();
    int base = blockIdx.x * CHUNK;
    for (int i = threadIdx.x; i < CHUNK; i += 256) {
        int s = src[base + i], d = dst[base + i];
        int pos = atomicAdd(&cursor[d >> 8], 1);
        ebuf[pos] = ((unsigned)s << 8) | (unsigned)(d & 255);
    }
}

// ---------------------------------------------------------------------------
// P4: fine counting-sort within each bin; fuses deg/dinv/rowstart
// ---------------------------------------------------------------------------
__launch_bounds__(256)
__global__ void k_fine(const unsigned int* __restrict__ ebuf, const int* __restrict__ off2,
                       int* __restrict__ esrc, int* __restrict__ rowstart,
                       float* __restrict__ dinv) {
    __shared__ int hist[256];
    __shared__ int tmp[256];
    __shared__ int nodeoff[256];
    __shared__ int cursor[256];
    __shared__ unsigned int ed[CAP];
    __shared__ int sOut[CAP];

    const int k = blockIdx.x;
    const int t = threadIdx.x;
    const int e0 = off2[k * NBLK3];
    const int e1 = (k + 1 < NBIN) ? off2[(k + 1) * NBLK3] : N_EDGES;
    int m = e1 - e0;
    if (m > CAP) m = CAP;

    hist[t] = 0;
    __syncthreads();
    for (int i = t; i < m; i += 256) {
        unsigned v = ebuf[e0 + i];
        ed[i] = v;
        atomicAdd(&hist[v & 255], 1);
    }
    __syncthreads();

    int v = hist[t];
    tmp[t] = v;
    __syncthreads();
    #pragma unroll
    for (int off = 1; off < 256; off <<= 1) {
        int p = (t >= off) ? tmp[t - off] : 0;
        __syncthreads();
        tmp[t] += p;
        __syncthreads();
    }
    nodeoff[t] = tmp[t] - v;
    cursor[t] = tmp[t] - v;
    __syncthreads();

    for (int i = t; i < m; i += 256) {
        unsigned e = ed[i];
        int pos = atomicAdd(&cursor[e & 255], 1);
        sOut[pos] = (int)(e >> 8);
    }
    __syncthreads();

    for (int i = t; i < m; i += 256) esrc[e0 + i] = sOut[i];

    int n = k * 256 + t;
    if (n < N_NODES) {
        rowstart[n] = e0 + nodeoff[t];
        dinv[n] = rsqrtf((float)hist[t] + 1.0f);
    }
    if (k == 0 && t == 0) rowstart[N_NODES] = N_EDGES;
}

// ---------------------------------------------------------------------------
// k_prep: transpose weights to bf16 [n][k] once.
// blocks 0..31: W1 (256x128) -> w1t[128][256]; blocks 32..39: W2 -> w2t[64][128]
// ---------------------------------------------------------------------------
__launch_bounds__(256)
__global__ void k_prep(const float* __restrict__ W1, const float* __restrict__ W2,
                       __bf16* __restrict__ w1t, __bf16* __restrict__ w2t) {
    __shared__ float tile[32][33];
    int b = blockIdx.x;
    const float* W; __bf16* WT; int ldw, ldt, k0, n0;
    if (b < 32) { W = W1; WT = w1t; ldw = HIDDEN; ldt = IN_DIM;
                  k0 = (b >> 2) * 32; n0 = (b & 3) * 32; }
    else { b -= 32; W = W2; WT = w2t; ldw = OUT_DIM; ldt = HIDDEN;
           k0 = (b >> 1) * 32; n0 = (b & 1) * 32; }
    int t = threadIdx.x;
    int r = t >> 3, c4 = (t & 7) * 4;
    float4 v = *(const float4*)&W[(k0 + r) * ldw + n0 + c4];
    tile[r][c4 + 0] = v.x; tile[r][c4 + 1] = v.y;
    tile[r][c4 + 2] = v.z; tile[r][c4 + 3] = v.w;
    __syncthreads();
    bf16x4 o;
    o[0] = (__bf16)tile[c4 + 0][r]; o[1] = (__bf16)tile[c4 + 1][r];
    o[2] = (__bf16)tile[c4 + 2][r]; o[3] = (__bf16)tile[c4 + 3][r];
    *(bf16x4*)&WT[(n0 + r) * ldt + k0 + c4] = o;
}

// ---------------------------------------------------------------------------
// GEMM1: H[M][128] = bf16(X) @ W1.  Block 128x128, 4 waves 2x2, wave 64x64.
// A staged in fragment-major LDS (pad-17 groups: conflict-free b128 r/w);
// B-fragments direct from L2-resident w1t[n][k]. BK=128 -> 2 chunks, 4 barriers.
// ---------------------------------------------------------------------------
__launch_bounds__(256, 2)
__global__ void k_gemm1(const float* __restrict__ X, const __bf16* __restrict__ w1t,
                        __bf16* __restrict__ H) {
    // groups g = rowblock*16 + kchunk (rowblock=row>>4 in 0..7, kchunk=0..15)
    // addr = (g*17 + (row&15)) * 8 bf16   -> 128*17*8 bf16 = 34816 B
    __shared__ __attribute__((aligned(16))) __bf16 As[128 * 17 * 8];

    const int t = threadIdx.x;
    const int wave = t >> 6;
    const int lane = t & 63;
    const int wr = wave >> 1, wc = wave & 1;
    const int lm = lane & 15;
    const int q = lane >> 4;
    const int row0 = blockIdx.x * 128;
    const int colbase = wc * 64;

    f32x4 acc[4][4] = {};

    #pragma unroll
    for (int chunk = 0; chunk < 2; ++chunk) {
        const int k0 = chunk * 128;
        // stage A: it 0..7, row = it*16 + (t>>4), kchunk = t&15 (8 k each)
        #pragma unroll
        for (int it = 0; it < 8; ++it) {
            int row = it * 16 + (t >> 4);
            int kc = t & 15;
            int grow = row0 + row;
            if (grow > N_NODES - 1) grow = N_NODES - 1;
            const float* xr = &X[grow * IN_DIM + k0 + kc * 8];
            float4 a0 = *(const float4*)&xr[0];
            float4 a1 = *(const float4*)&xr[4];
            bf16x8 f;
            f[0] = (__bf16)a0.x; f[1] = (__bf16)a0.y;
            f[2] = (__bf16)a0.z; f[3] = (__bf16)a0.w;
            f[4] = (__bf16)a1.x; f[5] = (__bf16)a1.y;
            f[6] = (__bf16)a1.z; f[7] = (__bf16)a1.w;
            int g = it * 16 + kc;                 // (row>>4)=it, kchunk=kc
            *(bf16x8*)&As[(g * 17 + (t >> 4)) * 8] = f;
        }
        __syncthreads();

        #pragma unroll
        for (int ks = 0; ks < 4; ++ks) {
            bf16x8 af[4], bfr[4];
            #pragma unroll
            for (int mi = 0; mi < 4; ++mi) {
                int g = (wr * 4 + mi) * 16 + ks * 4 + q;
                af[mi] = *(const bf16x8*)&As[(g * 17 + lm) * 8];
            }
            #pragma unroll
            for (int ni = 0; ni < 4; ++ni)
                bfr[ni] = *(const bf16x8*)
                    &w1t[(colbase + ni * 16 + lm) * IN_DIM + k0 + ks * 32 + q * 8];
            #pragma unroll
            for (int mi = 0; mi < 4; ++mi)
                #pragma unroll
                for (int ni = 0; ni < 4; ++ni)
                    acc[mi][ni] = __builtin_amdgcn_mfma_f32_16x16x32_bf16(
                        af[mi], bfr[ni], acc[mi][ni], 0, 0, 0);
        }
        __syncthreads();
    }

    #pragma unroll
    for (int mi = 0; mi < 4; ++mi) {
        #pragma unroll
        for (int r = 0; r < 4; ++r) {
            int grow = row0 + wr * 64 + mi * 16 + q * 4 + r;
            if (grow < N_NODES) {
                #pragma unroll
                for (int ni = 0; ni < 4; ++ni)
                    H[grow * HIDDEN + colbase + ni * 16 + lm] = (__bf16)acc[mi][ni][r];
            }
        }
    }
}

// ---------------------------------------------------------------------------
// gather layer1 (unchanged): 16 lanes x bf16x8 per node, unroll x4
// ---------------------------------------------------------------------------
__launch_bounds__(256)
__global__ void k_gather1(const int* __restrict__ rowstart, const int* __restrict__ esrc,
                          const float* __restrict__ dinv,
                          const __bf16* __restrict__ H, const float* __restrict__ b1,
                          __bf16* __restrict__ AGG) {
    int n = blockIdx.x * 16 + (threadIdx.x >> 4);
    if (n >= N_NODES) return;
    int j = (threadIdx.x & 15) * 8;

    float dn = dinv[n];
    float s = dn * dn;
    bf16x8 h = *(const bf16x8*)&H[n * HIDDEN + j];
    float acc[8];
    #pragma unroll
    for (int i = 0; i < 8; ++i) acc[i] = (float)h[i] * s;

    int p0 = rowstart[n], p1 = rowstart[n + 1];
    int p = p0;
    for (; p + 3 < p1; p += 4) {
        int s0 = esrc[p + 0], s1 = esrc[p + 1], s2 = esrc[p + 2], s3 = esrc[p + 3];
        float c0 = dinv[s0] * dn, c1 = dinv[s1] * dn;
        float c2 = dinv[s2] * dn, c3 = dinv[s3] * dn;
        bf16x8 v0 = *(const bf16x8*)&H[s0 * HIDDEN + j];
        bf16x8 v1 = *(const bf16x8*)&H[s1 * HIDDEN + j];
        bf16x8 v2 = *(const bf16x8*)&H[s2 * HIDDEN + j];
        bf16x8 v3 = *(const bf16x8*)&H[s3 * HIDDEN + j];
        #pragma unroll
        for (int i = 0; i < 8; ++i) acc[i] = fmaf((float)v0[i], c0, acc[i]);
        #pragma unroll
        for (int i = 0; i < 8; ++i) acc[i] = fmaf((float)v1[i], c1, acc[i]);
        #pragma unroll
        for (int i = 0; i < 8; ++i) acc[i] = fmaf((float)v2[i], c2, acc[i]);
        #pragma unroll
        for (int i = 0; i < 8; ++i) acc[i] = fmaf((float)v3[i], c3, acc[i]);
    }
    for (; p < p1; ++p) {
        int sidx = esrc[p];
        float c = dinv[sidx] * dn;
        bf16x8 v = *(const bf16x8*)&H[sidx * HIDDEN + j];
        #pragma unroll
        for (int i = 0; i < 8; ++i) acc[i] = fmaf((float)v[i], c, acc[i]);
    }

    float4 bb0 = *(const float4*)&b1[j];
    float4 bb1 = *(const float4*)&b1[j + 4];
    bf16x8 o;
    o[0] = (__bf16)fmaxf(acc[0] + bb0.x, 0.f);
    o[1] = (__bf16)fmaxf(acc[1] + bb0.y, 0.f);
    o[2] = (__bf16)fmaxf(acc[2] + bb0.z, 0.f);
    o[3] = (__bf16)fmaxf(acc[3] + bb0.w, 0.f);
    o[4] = (__bf16)fmaxf(acc[4] + bb1.x, 0.f);
    o[5] = (__bf16)fmaxf(acc[5] + bb1.y, 0.f);
    o[6] = (__bf16)fmaxf(acc[6] + bb1.z, 0.f);
    o[7] = (__bf16)fmaxf(acc[7] + bb1.w, 0.f);
    *(bf16x8*)&AGG[n * HIDDEN + j] = o;
}

// ---------------------------------------------------------------------------
// GEMM2: H2[M][64] = AGG @ W2.  Block 256 rows x 64 cols, 4 waves m-stacked,
// wave 64x64. Fragment-major LDS A (pad-17), B direct from w2t. BK=64, 2 chunks.
// ---------------------------------------------------------------------------
__launch_bounds__(256, 2)
__global__ void k_gemm2(const __bf16* __restrict__ AGG, const __bf16* __restrict__ w2t,
                        __bf16* __restrict__ H2) {
    // groups g = rowblock*8 + kchunk (rowblock=row>>4 in 0..15, kchunk=0..7)
    __shared__ __attribute__((aligned(16))) __bf16 As[128 * 17 * 8];  // 34816 B

    const int t = threadIdx.x;
    const int wave = t >> 6;
    const int lane = t & 63;
    const int lm = lane & 15;
    const int q = lane >> 4;
    const int row0 = blockIdx.x * 256;

    f32x4 acc[4][4] = {};

    #pragma unroll
    for (int chunk = 0; chunk < 2; ++chunk) {
        const int k0 = chunk * 64;
        // stage A: it 0..7, row = it*32 + (t>>3), kchunk = t&7 (8 bf16 each)
        #pragma unroll
        for (int it = 0; it < 8; ++it) {
            int row = it * 32 + (t >> 3);
            int kc = t & 7;
            int grow = row0 + row;
            if (grow > N_NODES - 1) grow = N_NODES - 1;
            bf16x8 f = *(const bf16x8*)&AGG[grow * HIDDEN + k0 + kc * 8];
            int g = (row >> 4) * 8 + kc;
            *(bf16x8*)&As[(g * 17 + (row & 15)) * 8] = f;
        }
        __syncthreads();

        #pragma unroll
        for (int ks = 0; ks < 2; ++ks) {
            bf16x8 af[4], bfr[4];
            #pragma unroll
            for (int mi = 0; mi < 4; ++mi) {
                int g = (wave * 4 + mi) * 8 + ks * 4 + q;
                af[mi] = *(const bf16x8*)&As[(g * 17 + lm) * 8];
            }
            #pragma unroll
            for (int ni = 0; ni < 4; ++ni)
                bfr[ni] = *(const bf16x8*)
                    &w2t[(ni * 16 + lm) * HIDDEN + k0 + ks * 32 + q * 8];
            #pragma unroll
            for (int mi = 0; mi < 4; ++mi)
                #pragma unroll
                for (int ni = 0; ni < 4; ++ni)
                    acc[mi][ni] = __builtin_amdgcn_mfma_f32_16x16x32_bf16(
                        af[mi], bfr[ni], acc[mi][ni], 0, 0, 0);
        }
        __syncthreads();
    }

    #pragma unroll
    for (int mi = 0; mi < 4; ++mi) {
        #pragma unroll
        for (int r = 0; r < 4; ++r) {
            int grow = row0 + wave * 64 + mi * 16 + q * 4 + r;
            if (grow < N_NODES) {
                #pragma unroll
                for (int ni = 0; ni < 4; ++ni)
                    H2[grow * OUT_DIM + ni * 16 + lm] = (__bf16)acc[mi][ni][r];
            }
        }
    }
}

// ---------------------------------------------------------------------------
// gather layer2 (unchanged): 8 lanes x bf16x8 per node, unroll x4
// ---------------------------------------------------------------------------
__launch_bounds__(256)
__global__ void k_gather2(const int* __restrict__ rowstart, const int* __restrict__ esrc,
                          const float* __restrict__ dinv,
                          const __bf16* __restrict__ H2, const float* __restrict__ b2,
                          float* __restrict__ OUT) {
    int n = blockIdx.x * 32 + (threadIdx.x >> 3);
    if (n >= N_NODES) return;
    int j = (threadIdx.x & 7) * 8;

    float dn = dinv[n];
    float s = dn * dn;
    bf16x8 h = *(const bf16x8*)&H2[n * OUT_DIM + j];
    float acc[8];
    #pragma unroll
    for (int i = 0; i < 8; ++i) acc[i] = (float)h[i] * s;

    int p0 = rowstart[n], p1 = rowstart[n + 1];
    int p = p0;
    for (; p + 3 < p1; p += 4) {
        int s0 = esrc[p + 0], s1 = esrc[p + 1], s2 = esrc[p + 2], s3 = esrc[p + 3];
        float c0 = dinv[s0] * dn, c1 = dinv[s1] * dn;
        float c2 = dinv[s2] * dn, c3 = dinv[s3] * dn;
        bf16x8 v0 = *(const bf16x8*)&H2[s0 * OUT_DIM + j];
        bf16x8 v1 = *(const bf16x8*)&H2[s1 * OUT_DIM + j];
        bf16x8 v2 = *(const bf16x8*)&H2[s2 * OUT_DIM + j];
        bf16x8 v3 = *(const bf16x8*)&H2[s3 * OUT_DIM + j];
        #pragma unroll
        for (int i = 0; i < 8; ++i) acc[i] = fmaf((float)v0[i], c0, acc[i]);
        #pragma unroll
        for (int i = 0; i < 8; ++i) acc[i] = fmaf((float)v1[i], c1, acc[i]);
        #pragma unroll
        for (int i = 0; i < 8; ++i) acc[i] = fmaf((float)v2[i], c2, acc[i]);
        #pragma unroll
        for (int i = 0; i < 8; ++i) acc[i] = fmaf((float)v3[i], c3, acc[i]);
    }
    for (; p < p1; ++p) {
        int sidx = esrc[p];
        float c = dinv[sidx] * dn;
        bf16x8 v = *(const bf16x8*)&H2[sidx * OUT_DIM + j];
        #pragma unroll
        for (int i = 0; i < 8; ++i) acc[i] = fmaf((float)v[i], c, acc[i]);
    }

    float4 bb0 = *(const float4*)&b2[j];
    float4 bb1 = *(const float4*)&b2[j + 4];
    float4 o0, o1;
    o0.x = fmaxf(acc[0] + bb0.x, 0.f);
    o0.y = fmaxf(acc[1] + bb0.y, 0.f);
    o0.z = fmaxf(acc[2] + bb0.z, 0.f);
    o0.w = fmaxf(acc[3] + bb0.w, 0.f);
    o1.x = fmaxf(acc[4] + bb1.x, 0.f);
    o1.y = fmaxf(acc[5] + bb1.y, 0.f);
    o1.z = fmaxf(acc[6] + bb1.z, 0.f);
    o1.w = fmaxf(acc[7] + bb1.w, 0.f);
    *(float4*)&OUT[n * OUT_DIM + j] = o0;
    *(float4*)&OUT[n * OUT_DIM + j + 4] = o1;
}

extern "C" void kernel_launch(void* const* d_in, const int* in_sizes, int n_in,
                              void* d_out, int out_size, void* d_ws, size_t ws_size,
                              hipStream_t stream) {
    const float* x  = (const float*)d_in[0];
    const int* ei   = (const int*)d_in[1];
    const float* W1 = (const float*)d_in[2];
    const float* b1 = (const float*)d_in[3];
    const float* W2 = (const float*)d_in[4];
    const float* b2 = (const float*)d_in[5];
    float* out = (float*)d_out;

    const int* src = ei;
    const int* dst = ei + N_EDGES;

    char* ws = (char*)d_ws;
    int*          cnt2     = (int*)         (ws + 0x000000);   // 400,384 B
    int*          bsum     = (int*)         (ws + 0x080000);
    int*          rowstart = (int*)         (ws + 0x090000);
    float*        dinv     = (float*)       (ws + 0x100000);
    unsigned int* ebuf     = (unsigned int*)(ws + 0x180000);   // 6.4 MB
    int*          esrc     = (int*)         (ws + 0x800000);   // 6.4 MB
    __bf16*       h1       = (__bf16*)      (ws + 0xE80000);   // 25.6 MB
    __bf16*       agg1     = (__bf16*)      (ws + 0x2880000);  // 25.6 MB
    __bf16*       h2       = (__bf16*)      (ws + 0x4280000);  // 12.8 MB
    __bf16*       w1t      = (__bf16*)      (ws + 0x4F00000);  // 64 KB
    __bf16*       w2t      = (__bf16*)      (ws + 0x4F20000);  // 16 KB

    // weight transpose (once) + CSR build
    k_prep<<<40, 256, 0, stream>>>(W1, W2, w1t, w2t);
    k_hist<<<NBLK3, 256, 0, stream>>>(dst, cnt2);
    k_scan1<<<NBLK_SCAN, 256, 0, stream>>>(cnt2, bsum);
    k_scan2<<<1, 512, 0, stream>>>(bsum);
    k_scan3<<<NBLK_SCAN, 256, 0, stream>>>(cnt2, bsum);
    k_scatter_bins<<<NBLK3, 256, 0, stream>>>(src, dst, cnt2, ebuf);
    k_fine<<<NBIN, 256, 0, stream>>>(ebuf, cnt2, esrc, rowstart, dinv);

    // layer 1
    k_gemm1<<<(N_NODES + 127) / 128, 256, 0, stream>>>(x, w1t, h1);
    k_gather1<<<(N_NODES + 15) / 16, 256, 0, stream>>>(rowstart, esrc, dinv, h1, b1, agg1);
    // layer 2
    k_gemm2<<<(N_NODES + 255) / 256, 256, 0, stream>>>(agg1, w2t, h2);
    k_gather2<<<(N_NODES + 31) / 32, 256, 0, stream>>>(rowstart, esrc, dinv, h2, b2, out);
}